// Round 13
// baseline (371.212 us; speedup 1.0000x reference)
//
#include <hip/hip_runtime.h>
#include <math.h>

#define Lnum 3
#define Mdim 4096
#define Pdim 4
#define Gdim 4
#define NIN 8192
#define NOUT 1000
#define Bdim 2048
#define Fdim 6
#define CIN 2048      // input channels per group (all layers)
#define MG 1024       // M / G
#define CH 2048       // M / K
#define DNEXT 8192
#define NRCHUNK (Bdim / 128)   // 16 row-blocks of 128 = GEMM tile rows

typedef short bf16x8 __attribute__((ext_vector_type(8)));
typedef float f32x4 __attribute__((ext_vector_type(4)));

__device__ __forceinline__ short f2bf(float f) {
    union { float f; unsigned u; } v; v.f = f;
    unsigned u = v.u;
    unsigned r = (u + 0x7fffu + ((u >> 16) & 1u)) >> 16;
    return (short)r;
}
__device__ __forceinline__ float bf2f(short h) {
    union { unsigned u; float f; } x;
    x.u = ((unsigned)(unsigned short)h) << 16;
    return x.f;
}

// ---------------------------------------------------------------------------
// Fused prep: W convert | Wo convert+pad | x regroup | perm remap | alpha SM.
// One launch, block ranges select the section (branch is block-uniform).
//   [0,12288)        W:   3*G*MG*CIN/8 chunks
//   [12288,16384)    Wo:  1024*1024 chunks (rows >= NOUT zero)
//   [16384,32768)    x:   B*CIN threads, c=idx&2047, b=idx>>11
//   [32768,32960)    perm remap: L*P*M ints
//   32960            alpha softmax (12 rows)
// ---------------------------------------------------------------------------
__global__ __launch_bounds__(256) void prep_all(
    const float* __restrict__ W, short* __restrict__ Wlb3,
    const float* __restrict__ Wo, short* __restrict__ Wob,
    const float* __restrict__ x, short* __restrict__ hg,
    const int* __restrict__ perms, int* __restrict__ perm_g,
    const float* __restrict__ alpha, float* __restrict__ wsm)
{
    const int blk = blockIdx.x;
    const int tid = threadIdx.x;

    if (blk < 12288) {
        const int i = blk * 256 + tid;
        const float4* s = (const float4*)W + (size_t)i * 2;
        float4 v0 = s[0], v1 = s[1];
        bf16x8 o;
        o[0] = f2bf(v0.x); o[1] = f2bf(v0.y); o[2] = f2bf(v0.z); o[3] = f2bf(v0.w);
        o[4] = f2bf(v1.x); o[5] = f2bf(v1.y); o[6] = f2bf(v1.z); o[7] = f2bf(v1.w);
        *((bf16x8*)Wlb3 + i) = o;
    } else if (blk < 16384) {
        const int i = (blk - 12288) * 256 + tid;
        const int row = i >> 10;
        bf16x8 o;
        if (row < NOUT) {
            const float4* s = (const float4*)(Wo + (size_t)row * DNEXT + (i & 1023) * 8);
            float4 v0 = s[0], v1 = s[1];
            o[0] = f2bf(v0.x); o[1] = f2bf(v0.y); o[2] = f2bf(v0.z); o[3] = f2bf(v0.w);
            o[4] = f2bf(v1.x); o[5] = f2bf(v1.y); o[6] = f2bf(v1.z); o[7] = f2bf(v1.w);
        } else {
            for (int j = 0; j < 8; ++j) o[j] = 0;
        }
        *((bf16x8*)Wob + i) = o;
    } else if (blk < 32768) {
        const int idx = (blk - 16384) * 256 + tid;
        const int b = idx >> 11;
        const int c = idx & 2047;
        float4 v = *(const float4*)(x + (size_t)b * NIN + 4 * c);
        const size_t plane = (size_t)Bdim * CIN;
        hg[0 * plane + (size_t)b * CIN + c] = f2bf(v.x);
        hg[1 * plane + (size_t)b * CIN + c] = f2bf(v.y);
        hg[2 * plane + (size_t)b * CIN + c] = f2bf(v.z);
        hg[3 * plane + (size_t)b * CIN + c] = f2bf(v.w);
    } else if (blk < 32960) {
        const int i = (blk - 32768) * 256 + tid;   // < 49152 exactly
        int j  = perms[i];
        int jg = ((j & 3) << 10) | (j >> 2);
        perm_g[i] = jg ^ ((jg >> 3) & 3);
    } else {
        if (tid < Lnum * Pdim) {
            const float* a = alpha + tid * Fdim;
            float mx = a[0];
#pragma unroll
            for (int f = 1; f < Fdim; ++f) mx = fmaxf(mx, a[f]);
            float e[Fdim]; float s = 0.f;
#pragma unroll
            for (int f = 0; f < Fdim; ++f) { e[f] = __expf(a[f] - mx); s += e[f]; }
            const float inv = 1.f / s;
#pragma unroll
            for (int f = 0; f < Fdim; ++f) wsm[tid * Fdim + f] = e[f] * inv;
        }
    }
}

// ---------------------------------------------------------------------------
// MFMA bf16 GEMM, m97 structure: 4 waves (2x2), tile 128x128, each wave 64x64
// (4x4 16x16x32 frags), BK=32, SINGLE 16 KB LDS buffer, stage->sync->compute
// ->sync. Slot-XOR swizzle (slot ^ (row&3)) on both stage source and ds_read.
// If STATS: fused per-column partial sums -> psum/psumsq[by*Mdim+g*sgz+n0+col].
// ---------------------------------------------------------------------------
template<bool STATS, typename CT>
__global__ __launch_bounds__(256) void gemm_mfma(
    const short* __restrict__ A0, size_t aZ, int lda,
    const short* __restrict__ B0, size_t bZ, int ldb,
    const float* __restrict__ bias0, size_t biasZ,
    CT* __restrict__ C0, size_t cZ,
    int K, int ldc, int nbound,
    float* __restrict__ psum, float* __restrict__ psumsq, int sgz)
{
    // XCD-aware swizzle (nwg % 8 == 0 in all our launches)
    const int nx = gridDim.x, ny = gridDim.y;
    const int nwg = nx * ny * gridDim.z;
    const int lin = blockIdx.x + nx * (blockIdx.y + ny * blockIdx.z);
    int swz = (lin & 7) * (nwg >> 3) + (lin >> 3);
    const int bx = swz % nx; swz /= nx;
    const int by = swz % ny;
    const int g  = swz / ny;

    const short* A  = A0 + aZ * g;
    const short* Bm = B0 + bZ * g;
    CT* C = C0 + cZ * g;

    const int n0 = bx * 128;
    const int b0 = by * 128;

    __shared__ short As[128 * 32];   // 8 KB
    __shared__ short Bs[128 * 32];   // 8 KB

    const int tid  = threadIdx.x;
    const int w    = tid >> 6;
    const int lane = tid & 63;
    const int wr = w >> 1, wc = w & 1;

    f32x4 acc[4][4];
#pragma unroll
    for (int m = 0; m < 4; ++m)
#pragma unroll
        for (int n = 0; n < 4; ++n) acc[m][n] = (f32x4)0.f;

    const int fr15 = lane & 15;
    const int fq   = lane >> 4;

    // Stage one K-tile (32) : 128 rows x 4 16B-slots each for A and B.
    // Phys slot s of row r holds logical k-chunk (s ^ (r&3)).
    auto stage = [&](int k0) {
#pragma unroll
        for (int q = 0; q < 2; ++q) {
            const int idx = tid + q * 256;
            const int r = idx >> 2, slot = idx & 3;
            const int gs = slot ^ (r & 3);
            const short* ga = A + (size_t)(b0 + r) * lda + k0 + gs * 8;
            __builtin_amdgcn_global_load_lds(
                (const __attribute__((address_space(1))) void*)ga,
                (__attribute__((address_space(3))) void*)(&As[idx * 8]), 16, 0, 0);
        }
#pragma unroll
        for (int q = 0; q < 2; ++q) {
            const int idx = tid + q * 256;
            const int r = idx >> 2, slot = idx & 3;
            const int gs = slot ^ (r & 3);
            const short* gb = Bm + (size_t)(n0 + r) * ldb + k0 + gs * 8;
            __builtin_amdgcn_global_load_lds(
                (const __attribute__((address_space(1))) void*)gb,
                (__attribute__((address_space(3))) void*)(&Bs[idx * 8]), 16, 0, 0);
        }
    };

    auto compute = [&]() {
        bf16x8 af[4], bff[4];
#pragma unroll
        for (int m = 0; m < 4; ++m) {
            const int r = wr * 64 + m * 16 + fr15;
            const int s = fq ^ (r & 3);
            af[m] = *(const bf16x8*)(&As[r * 32 + s * 8]);
        }
#pragma unroll
        for (int n = 0; n < 4; ++n) {
            const int r = wc * 64 + n * 16 + fr15;
            const int s = fq ^ (r & 3);
            bff[n] = *(const bf16x8*)(&Bs[r * 32 + s * 8]);
        }
#pragma unroll
        for (int m = 0; m < 4; ++m)
#pragma unroll
            for (int n = 0; n < 4; ++n)
                acc[m][n] = __builtin_amdgcn_mfma_f32_16x16x32_bf16(af[m], bff[n], acc[m][n], 0, 0, 0);
    };

    const int nt = K >> 5;
    for (int t = 0; t < nt; ++t) {
        stage(t << 5);
        __syncthreads();
        compute();
        __syncthreads();
    }

    float s[4], ss[4];
#pragma unroll
    for (int n = 0; n < 4; ++n) { s[n] = 0.f; ss[n] = 0.f; }

#pragma unroll
    for (int m = 0; m < 4; ++m) {
#pragma unroll
        for (int n = 0; n < 4; ++n) {
#pragma unroll
            for (int j = 0; j < 4; ++j) {
                const int row = b0 + wr * 64 + m * 16 + fq * 4 + j;
                const int col = n0 + wc * 64 + n * 16 + fr15;
                if (col < nbound) {
                    float v = acc[m][n][j];
                    if (bias0) v += bias0[biasZ * g + col];
                    C[(size_t)row * ldc + col] = (CT)(sizeof(CT) == 2 ? (CT)f2bf(v) : (CT)v);
                    if (STATS) { s[n] += v; ss[n] += v * v; }
                }
            }
        }
    }

    if (STATS) {
        // As/Bs free now (loop ended with syncthreads after last compute...
        // need one more barrier to be safe across waves before reuse)
        __syncthreads();
        float* sum_lds = (float*)&As[0];          // 128 cols x 8 slots
        float* ssq_lds = sum_lds + 128 * 8;       // 4 KB + 4 KB = within As+Bs
        const int slot = wr * 4 + fq;
#pragma unroll
        for (int n = 0; n < 4; ++n) {
            const int cl = wc * 64 + n * 16 + fr15;
            sum_lds[cl * 8 + slot] = s[n];
            ssq_lds[cl * 8 + slot] = ss[n];
        }
        __syncthreads();
        for (int cl = tid; cl < 128; cl += 256) {
            float a = 0.f, b = 0.f;
#pragma unroll
            for (int q = 0; q < 8; ++q) {
                a += sum_lds[cl * 8 + q];
                b += ssq_lds[cl * 8 + q];
            }
            const size_t o = (size_t)by * Mdim + g * sgz + n0 + cl;
            psum[o]   = a;
            psumsq[o] = b;
        }
    }
}

// out[b,n] = sum_z p[z][b,n] + bo[n], 4 split-K partials
__global__ __launch_bounds__(256) void reduce_out(
    const float* __restrict__ part, const float* __restrict__ bo,
    float* __restrict__ out)
{
    const int n = blockIdx.x * 256 + threadIdx.x;
    const int b = blockIdx.y;
    if (n >= NOUT) return;
    const size_t S = (size_t)Bdim * 1024;
    const size_t i = (size_t)b * 1024 + n;
    out[(size_t)b * NOUT + n] =
        part[i] + part[S + i] + part[2 * S + i] + part[3 * S + i] + bo[n];
}

// ---------------------------------------------------------------------------
// Columns are in GROUPED order jg = g*1024+m  (orig j = (jg&1023)*4 + jg>>10)
__global__ __launch_bounds__(256) void bn_finalize(
    const float* __restrict__ psum, const float* __restrict__ psumsq,
    const float* __restrict__ gamma, const float* __restrict__ beta,
    float* __restrict__ scale, float* __restrict__ shift)
{
    const int jg = blockIdx.x * 256 + threadIdx.x;
    if (jg >= Mdim) return;
    const int j = ((jg & 1023) << 2) | (jg >> 10);
    float s = 0.f, ss = 0.f;
    for (int r = 0; r < NRCHUNK; ++r) {
        s  += psum[r * Mdim + jg];
        ss += psumsq[r * Mdim + jg];
    }
    const float mu  = s * (1.f / Bdim);
    const float var = ss * (1.f / Bdim) - mu * mu;
    const float sc  = gamma[j] * rsqrtf(var + 1e-5f);
    scale[jg] = sc;
    shift[jg] = beta[j] - mu * sc;
}

// ---------------------------------------------------------------------------
// Fused normalize + gather + combinact, 2 rows/block, 512 threads (8 waves).
// E=e^z precomputed at staging:
//   sig(z0)*sig(z1) = E0*E1/((1+E0)(1+E1));  lse = LN2*log2(E0+E1).
// LDS: per col f32x4 {z_r0, z_r1, E_r0, E_r1}, bank-swizzled (perm pre-folded).
// MODE 0: grouped planes hg[g][b][p*512+q], c=q*4+g ; MODE 1: flat h[b][p*CH+c]
// ---------------------------------------------------------------------------
template<int MODE>
__global__ __launch_bounds__(512) void combinact_kernel(
    const short* __restrict__ Y, const float* __restrict__ scale,
    const float* __restrict__ shift, const int* __restrict__ perm,
    const float* __restrict__ wsm, short* __restrict__ out)
{
    __shared__ f32x4 zE[Mdim];           // 64 KB
    const int b0  = blockIdx.x * 2;
    const int tid = threadIdx.x;
    const float L2E = 1.44269504f;
    const float LN2 = 0.69314718f;

    {
        const int i8   = tid;            // 512 chunks of 8 cols, 1 per thread
        const int base = i8 * 8;
        const bf16x8 v0 = *((const bf16x8*)(Y + (size_t)(b0 + 0) * Mdim) + i8);
        const bf16x8 v1 = *((const bf16x8*)(Y + (size_t)(b0 + 1) * Mdim) + i8);
        const int xr = i8 & 3;           // bank swizzle: js = j ^ ((j>>3)&3)
#pragma unroll
        for (int jj = 0; jj < 8; ++jj) {
            const float sc = scale[base + jj];
            const float sh = shift[base + jj];
            f32x4 t;
            t[0] = bf2f(v0[jj]) * sc + sh;
            t[1] = bf2f(v1[jj]) * sc + sh;
            t[2] = __builtin_amdgcn_exp2f(L2E * t[0]);
            t[3] = __builtin_amdgcn_exp2f(L2E * t[1]);
            zE[base + (jj ^ xr)] = t;
        }
    }
    __syncthreads();

    float wv[Pdim][Fdim];
#pragma unroll
    for (int p = 0; p < Pdim; ++p)
#pragma unroll
        for (int f = 0; f < Fdim; ++f) wv[p][f] = wsm[p * Fdim + f];

    const size_t plane = (size_t)Bdim * CIN;

#pragma unroll
    for (int k = 0; k < 4; ++k) {
        const int idx = k * 512 + tid;
        int c, g = 0, q = 0;
        if (MODE == 0) { g = idx >> 9; q = idx & 511; c = q * 4 + g; }
        else           { c = idx; }

#pragma unroll
        for (int p = 0; p < Pdim; ++p) {
            const int2 jj = *(const int2*)(perm + p * Mdim + 2 * c);
            const f32x4 c0 = zE[jj.x];
            const f32x4 c1 = zE[jj.y];

#pragma unroll
            for (int r = 0; r < 2; ++r) {
                const float z0 = c0[r],     z1 = c1[r];
                const float E0 = c0[2 + r], E1 = c1[2 + r];

                const float mx = fmaxf(z0, z1);
                const float pr = z0 * z1;
                const float a1 = copysignf(__builtin_amdgcn_sqrtf(fabsf(pr) + 1e-12f), pr);
                const float a2 = z0 * E0 * E1 *
                                 __builtin_amdgcn_rcpf((1.f + E0) * (1.f + E1));
                const float a3 = __builtin_amdgcn_sqrtf(z0 * z0 + z1 * z1 + 1e-12f);
                const float a4 = fmaxf(fabsf(z0), fabsf(z1));
                const float a5 = LN2 * __builtin_amdgcn_logf(E0 + E1);

                const float v = wv[p][0] * mx + wv[p][1] * a1 + wv[p][2] * a2 +
                                wv[p][3] * a3 + wv[p][4] * a4 + wv[p][5] * a5;

                if (MODE == 0)
                    out[g * plane + (size_t)(b0 + r) * CIN + p * 512 + q] = f2bf(v);
                else
                    out[(size_t)(b0 + r) * DNEXT + p * CH + c] = f2bf(v);
            }
        }
    }
}

// ---------------------------------------------------------------------------
extern "C" void kernel_launch(void* const* d_in, const int* in_sizes, int n_in,
                              void* d_out, int out_size, void* d_ws, size_t ws_size,
                              hipStream_t stream)
{
    const float* x     = (const float*)d_in[0];
    const int*   perms = (const int*)  d_in[1];
    const float* W     = (const float*)d_in[2];
    const float* bvec  = (const float*)d_in[3];
    const float* gamma = (const float*)d_in[4];
    const float* beta  = (const float*)d_in[5];
    const float* alpha = (const float*)d_in[6];
    const float* Wo    = (const float*)d_in[7];
    const float* bo    = (const float*)d_in[8];
    float* out = (float*)d_out;

    char* ws = (char*)d_ws;
    short* y      = (short*)ws;                             // B*M bf16 (grouped cols)
    short* hg     = y + (size_t)Bdim * Mdim;                // G*B*CIN bf16 (also hflat)
    short* Wlb3   = hg + (size_t)Gdim * Bdim * CIN;         // 3*G*MG*CIN bf16 (all layers)
    short* Wob    = Wlb3 + (size_t)Lnum * Gdim * MG * CIN;  // 1024*8192 bf16
    float* psum   = (float*)(Wob + (size_t)1024 * DNEXT);
    float* psumsq = psum + (size_t)NRCHUNK * Mdim;
    float* scale  = psumsq + (size_t)NRCHUNK * Mdim;
    float* shift  = scale + Mdim;
    float* wsm    = shift + Mdim;
    int*   perm_g = (int*)(wsm + Lnum * Pdim * Fdim);       // L*P*M ints

    short* hflat = hg;           // layer-2 combinact output aliases hg (dead then)
    float* part  = (float*)Wlb3; // out-GEMM partials alias Wlb3 (dead then), 32 MB

    prep_all<<<32961, 256, 0, stream>>>(
        W, Wlb3, Wo, Wob, x, hg, perms, perm_g, alpha, wsm);

    const size_t planeA = (size_t)Bdim * CIN;
    const size_t planeB = (size_t)MG * CIN;

    for (int l = 0; l < Lnum; ++l) {
        // y[b][g*1024+m] bf16, contiguous stores; BN partial stats fused.
        dim3 gg(MG / 128, Bdim / 128, Gdim);
        gemm_mfma<true, short><<<gg, 256, 0, stream>>>(
            hg, planeA, CIN, Wlb3 + (size_t)l * Gdim * MG * CIN, planeB, CIN,
            bvec + (size_t)l * Gdim * MG, (size_t)MG,
            y, (size_t)MG,
            CIN, Mdim, MG,
            psum, psumsq, MG);

        bn_finalize<<<Mdim / 256, 256, 0, stream>>>(
            psum, psumsq, gamma + (size_t)l * Mdim, beta + (size_t)l * Mdim, scale, shift);

        if (l < Lnum - 1)
            combinact_kernel<0><<<Bdim / 2, 512, 0, stream>>>(
                y, scale, shift, perm_g + (size_t)l * Pdim * Mdim, wsm + l * Pdim * Fdim, hg);
        else
            combinact_kernel<1><<<Bdim / 2, 512, 0, stream>>>(
                y, scale, shift, perm_g + (size_t)l * Pdim * Mdim, wsm + l * Pdim * Fdim, hflat);
    }

    // Output GEMM, split-K=4 (K=2048 each), partials in Wlb3 region, then reduce.
    dim3 go(1024 / 128, Bdim / 128, 4);
    gemm_mfma<false, float><<<go, 256, 0, stream>>>(
        hflat, (size_t)2048, DNEXT, Wob, (size_t)2048, DNEXT,
        nullptr, 0,
        part, (size_t)Bdim * 1024,
        2048, 1024, 1024,
        nullptr, nullptr, 0);

    dim3 gr(4, Bdim);
    reduce_out<<<gr, 256, 0, stream>>>(part, bo, out);
}

// Round 14
// 330.393 us; speedup vs baseline: 1.1235x; 1.1235x over previous
//
#include <hip/hip_runtime.h>
#include <math.h>

#define Lnum 3
#define Mdim 4096
#define Pdim 4
#define Gdim 4
#define NIN 8192
#define NOUT 1000
#define Bdim 2048
#define Fdim 6
#define CIN 2048      // input channels per group (all layers)
#define MG 1024       // M / G
#define CH 2048       // M / K
#define DNEXT 8192
#define NRCHUNK (Bdim / 128)   // 16 row-blocks of 128 = GEMM tile rows

typedef short bf16x8 __attribute__((ext_vector_type(8)));
typedef float f32x4 __attribute__((ext_vector_type(4)));

__device__ __forceinline__ short f2bf(float f) {
    union { float f; unsigned u; } v; v.f = f;
    unsigned u = v.u;
    unsigned r = (u + 0x7fffu + ((u >> 16) & 1u)) >> 16;
    return (short)r;
}
__device__ __forceinline__ float bf2f(short h) {
    union { unsigned u; float f; } x;
    x.u = ((unsigned)(unsigned short)h) << 16;
    return x.f;
}

// ---------------------------------------------------------------------------
__global__ __launch_bounds__(256) void convert_f32_bf16(
    const float* __restrict__ src, short* __restrict__ dst, int n8)
{
    int i = blockIdx.x * 256 + threadIdx.x;
    if (i >= n8) return;
    const float4* s = (const float4*)src + (size_t)i * 2;
    float4 v0 = s[0], v1 = s[1];
    bf16x8 o;
    o[0] = f2bf(v0.x); o[1] = f2bf(v0.y); o[2] = f2bf(v0.z); o[3] = f2bf(v0.w);
    o[4] = f2bf(v1.x); o[5] = f2bf(v1.y); o[6] = f2bf(v1.z); o[7] = f2bf(v1.w);
    *((bf16x8*)dst + i) = o;
}

// Wo (1000 x 8192) f32 -> padded (1024 x 8192) bf16, pad rows zero
__global__ __launch_bounds__(256) void convert_wo(
    const float* __restrict__ src, short* __restrict__ dst)
{
    int i = blockIdx.x * 256 + threadIdx.x;
    int row = i >> 10;
    bf16x8 o;
    if (row < NOUT) {
        const float4* s = (const float4*)(src + (size_t)row * DNEXT + (i & 1023) * 8);
        float4 v0 = s[0], v1 = s[1];
        o[0] = f2bf(v0.x); o[1] = f2bf(v0.y); o[2] = f2bf(v0.z); o[3] = f2bf(v0.w);
        o[4] = f2bf(v1.x); o[5] = f2bf(v1.y); o[6] = f2bf(v1.z); o[7] = f2bf(v1.w);
    } else {
        for (int j = 0; j < 8; ++j) o[j] = 0;
    }
    *((bf16x8*)dst + i) = o;
}

// x (B x 8192) f32 -> grouped bf16 planes hg[g][b][c] = x[b][4c+g]
__global__ __launch_bounds__(256) void x_to_grouped(
    const float* __restrict__ x, short* __restrict__ hg)
{
    const int c = blockIdx.x * 256 + threadIdx.x;
    const int b = blockIdx.y;
    float4 v = *(const float4*)(x + (size_t)b * NIN + 4 * c);
    const size_t plane = (size_t)Bdim * CIN;
    hg[0 * plane + (size_t)b * CIN + c] = f2bf(v.x);
    hg[1 * plane + (size_t)b * CIN + c] = f2bf(v.y);
    hg[2 * plane + (size_t)b * CIN + c] = f2bf(v.z);
    hg[3 * plane + (size_t)b * CIN + c] = f2bf(v.w);
}

// perm value remap: original j -> grouped col jg = (j&3)*1024 + (j>>2),
// then fold the combinact LDS bank swizzle: js = jg ^ ((jg>>3)&3).
__global__ __launch_bounds__(256) void remap_perms(
    const int* __restrict__ perm, int* __restrict__ perm_g, int n)
{
    int i = blockIdx.x * 256 + threadIdx.x;
    if (i >= n) return;
    int j  = perm[i];
    int jg = ((j & 3) << 10) | (j >> 2);
    perm_g[i] = jg ^ ((jg >> 3) & 3);
}

// ---------------------------------------------------------------------------
// MFMA bf16 GEMM, R12 loop structure with BK=32: both operands via
// global_load_lds (pre-swizzled source slot), double-buffered (2 x 16 KB),
// counted vmcnt(2) 2-deep pipeline. Tile 128x128, 8 waves (2x4), each wave
// 64x32 (4x2 frags). 32 KB LDS + 32-VGPR acc -> 4 blocks/CU (full 32 waves).
// If STATS: fused per-column partial sums -> psum/psumsq[by*Mdim+g*sgz+n0+col].
// ---------------------------------------------------------------------------
template<bool STATS, typename CT>
__global__ __launch_bounds__(512) void gemm_mfma(
    const short* __restrict__ A0, size_t aZ, int lda,
    const short* __restrict__ B0, size_t bZ, int ldb,
    const float* __restrict__ bias0, size_t biasZ,
    CT* __restrict__ C0, size_t cZ,
    int K, int ldc, int nbound,
    float* __restrict__ psum, float* __restrict__ psumsq, int sgz)
{
    // XCD-aware swizzle (nwg % 8 == 0 in all our launches)
    const int nx = gridDim.x, ny = gridDim.y;
    const int nwg = nx * ny * gridDim.z;
    const int lin = blockIdx.x + nx * (blockIdx.y + ny * blockIdx.z);
    int swz = (lin & 7) * (nwg >> 3) + (lin >> 3);
    const int bx = swz % nx; swz /= nx;
    const int by = swz % ny;
    const int g  = swz / ny;

    const short* A  = A0 + aZ * g;
    const short* Bm = B0 + bZ * g;
    CT* C = C0 + cZ * g;

    const int n0 = bx * 128;
    const int b0 = by * 128;

    __shared__ short As[2][128 * 32];   // 2 x 8 KB
    __shared__ short Bs[2][128 * 32];   // 2 x 8 KB

    const int tid  = threadIdx.x;
    const int w    = tid >> 6;
    const int lane = tid & 63;
    const int wr = w >> 2, wc = w & 3;   // 2 x 4 waves

    f32x4 acc[4][2];
#pragma unroll
    for (int m = 0; m < 4; ++m)
#pragma unroll
        for (int n = 0; n < 2; ++n) acc[m][n] = (f32x4)0.f;

    // Stage one K-tile (32): 128 rows x 4 16B-slots per operand; 512 threads
    // -> exactly 1 A-chunk + 1 B-chunk per thread (2 outstanding loads).
    // Phys slot s of row r holds logical k-chunk (s ^ (r&3)).
    const int srow  = tid >> 2;
    const int sslot = tid & 3;
    auto stage = [&](int buf, int k0) {
        const int gs = sslot ^ (srow & 3);
        const short* ga = A + (size_t)(b0 + srow) * lda + k0 + gs * 8;
        __builtin_amdgcn_global_load_lds(
            (const __attribute__((address_space(1))) void*)ga,
            (__attribute__((address_space(3))) void*)(&As[buf][tid * 8]), 16, 0, 0);
        const short* gb = Bm + (size_t)(n0 + srow) * ldb + k0 + gs * 8;
        __builtin_amdgcn_global_load_lds(
            (const __attribute__((address_space(1))) void*)gb,
            (__attribute__((address_space(3))) void*)(&Bs[buf][tid * 8]), 16, 0, 0);
    };

    const int fr15 = lane & 15;
    const int fq   = lane >> 4;

    auto compute = [&](int buf) {
        bf16x8 af[4], bff[2];
#pragma unroll
        for (int m = 0; m < 4; ++m) {
            const int r = wr * 64 + m * 16 + fr15;
            const int s = fq ^ (r & 3);
            af[m] = *(const bf16x8*)(&As[buf][r * 32 + s * 8]);
        }
#pragma unroll
        for (int n = 0; n < 2; ++n) {
            const int r = wc * 32 + n * 16 + fr15;
            const int s = fq ^ (r & 3);
            bff[n] = *(const bf16x8*)(&Bs[buf][r * 32 + s * 8]);
        }
#pragma unroll
        for (int m = 0; m < 4; ++m)
#pragma unroll
            for (int n = 0; n < 2; ++n)
                acc[m][n] = __builtin_amdgcn_mfma_f32_16x16x32_bf16(af[m], bff[n], acc[m][n], 0, 0, 0);
    };

    stage(0, 0);

    const int nt = K >> 5;   // even (K multiple of 64)
    int p = 0;
    for (int t = 0; t < nt - 1; ++t) {
        stage(p ^ 1, (t + 1) << 5);
        // wait for buf[p]'s 2 loads (issued last iter); the 2 just issued for
        // buf[p^1] stay in flight across both barriers.
        asm volatile("s_waitcnt vmcnt(2)" ::: "memory");
        __builtin_amdgcn_s_barrier();
        asm volatile("" ::: "memory");
        compute(p);
        asm volatile("" ::: "memory");
        __builtin_amdgcn_s_barrier();
        p ^= 1;
    }
    asm volatile("s_waitcnt vmcnt(0)" ::: "memory");
    __builtin_amdgcn_s_barrier();
    asm volatile("" ::: "memory");
    compute(p);

    float s[2], ss[2];
#pragma unroll
    for (int n = 0; n < 2; ++n) { s[n] = 0.f; ss[n] = 0.f; }

#pragma unroll
    for (int m = 0; m < 4; ++m) {
#pragma unroll
        for (int n = 0; n < 2; ++n) {
#pragma unroll
            for (int j = 0; j < 4; ++j) {
                const int row = b0 + wr * 64 + m * 16 + fq * 4 + j;
                const int col = n0 + wc * 32 + n * 16 + fr15;
                if (col < nbound) {
                    float v = acc[m][n][j];
                    if (bias0) v += bias0[biasZ * g + col];
                    C[(size_t)row * ldc + col] = (CT)(sizeof(CT) == 2 ? (CT)f2bf(v) : (CT)v);
                    if (STATS) { s[n] += v; ss[n] += v * v; }
                }
            }
        }
    }

    if (STATS) {
        __syncthreads();   // all waves done with LDS compute buffers
        float* sum_lds = (float*)&As[0][0];        // 128 cols x 8 slots (4 KB)
        float* ssq_lds = sum_lds + 128 * 8;        // next 4 KB (fits As[0])
        const int slot = wr * 4 + fq;
#pragma unroll
        for (int n = 0; n < 2; ++n) {
            const int cl = wc * 32 + n * 16 + fr15;
            sum_lds[cl * 8 + slot] = s[n];
            ssq_lds[cl * 8 + slot] = ss[n];
        }
        __syncthreads();
        for (int cl = tid; cl < 128; cl += 512) {
            float a = 0.f, b = 0.f;
#pragma unroll
            for (int q = 0; q < 8; ++q) {
                a += sum_lds[cl * 8 + q];
                b += ssq_lds[cl * 8 + q];
            }
            const size_t o = (size_t)by * Mdim + g * sgz + n0 + cl;
            psum[o]   = a;
            psumsq[o] = b;
        }
    }
}

// out[b,n] = sum_z p[z][b,n] + bo[n], 4 split-K partials
__global__ __launch_bounds__(256) void reduce_out(
    const float* __restrict__ part, const float* __restrict__ bo,
    float* __restrict__ out)
{
    const int n = blockIdx.x * 256 + threadIdx.x;
    const int b = blockIdx.y;
    if (n >= NOUT) return;
    const size_t S = (size_t)Bdim * 1024;
    const size_t i = (size_t)b * 1024 + n;
    out[(size_t)b * NOUT + n] =
        part[i] + part[S + i] + part[2 * S + i] + part[3 * S + i] + bo[n];
}

// ---------------------------------------------------------------------------
// Columns are in GROUPED order jg = g*1024+m  (orig j = (jg&1023)*4 + jg>>10)
__global__ __launch_bounds__(256) void bn_finalize(
    const float* __restrict__ psum, const float* __restrict__ psumsq,
    const float* __restrict__ gamma, const float* __restrict__ beta,
    float* __restrict__ scale, float* __restrict__ shift)
{
    const int jg = blockIdx.x * 256 + threadIdx.x;
    if (jg >= Mdim) return;
    const int j = ((jg & 1023) << 2) | (jg >> 10);
    float s = 0.f, ss = 0.f;
    for (int r = 0; r < NRCHUNK; ++r) {
        s  += psum[r * Mdim + jg];
        ss += psumsq[r * Mdim + jg];
    }
    const float mu  = s * (1.f / Bdim);
    const float var = ss * (1.f / Bdim) - mu * mu;
    const float sc  = gamma[j] * rsqrtf(var + 1e-5f);
    scale[jg] = sc;
    shift[jg] = beta[j] - mu * sc;
}

__global__ void alpha_softmax(const float* __restrict__ alpha, float* __restrict__ wsm)
{
    const int idx = threadIdx.x;
    if (idx >= Lnum * Pdim) return;
    const float* a = alpha + idx * Fdim;
    float mx = a[0];
#pragma unroll
    for (int f = 1; f < Fdim; ++f) mx = fmaxf(mx, a[f]);
    float e[Fdim]; float s = 0.f;
#pragma unroll
    for (int f = 0; f < Fdim; ++f) { e[f] = __expf(a[f] - mx); s += e[f]; }
    const float inv = 1.f / s;
#pragma unroll
    for (int f = 0; f < Fdim; ++f) wsm[idx * Fdim + f] = e[f] * inv;
}

// ---------------------------------------------------------------------------
// Fused normalize + gather + combinact, 2 rows/block, 512 threads (8 waves).
// E=e^z precomputed at staging:
//   sig(z0)*sig(z1) = E0*E1/((1+E0)(1+E1));  lse = LN2*log2(E0+E1).
// LDS: per col f32x4 {z_r0, z_r1, E_r0, E_r1}, bank-swizzled (perm pre-folded).
// MODE 0: grouped planes hg[g][b][p*512+q], c=q*4+g ; MODE 1: flat h[b][p*CH+c]
// ---------------------------------------------------------------------------
template<int MODE>
__global__ __launch_bounds__(512) void combinact_kernel(
    const short* __restrict__ Y, const float* __restrict__ scale,
    const float* __restrict__ shift, const int* __restrict__ perm,
    const float* __restrict__ wsm, short* __restrict__ out)
{
    __shared__ f32x4 zE[Mdim];           // 64 KB
    const int b0  = blockIdx.x * 2;
    const int tid = threadIdx.x;
    const float L2E = 1.44269504f;
    const float LN2 = 0.69314718f;

    {
        const int i8   = tid;            // 512 chunks of 8 cols, 1 per thread
        const int base = i8 * 8;
        const bf16x8 v0 = *((const bf16x8*)(Y + (size_t)(b0 + 0) * Mdim) + i8);
        const bf16x8 v1 = *((const bf16x8*)(Y + (size_t)(b0 + 1) * Mdim) + i8);
        const int xr = i8 & 3;           // bank swizzle: js = j ^ ((j>>3)&3)
#pragma unroll
        for (int jj = 0; jj < 8; ++jj) {
            const float sc = scale[base + jj];
            const float sh = shift[base + jj];
            f32x4 t;
            t[0] = bf2f(v0[jj]) * sc + sh;
            t[1] = bf2f(v1[jj]) * sc + sh;
            t[2] = __builtin_amdgcn_exp2f(L2E * t[0]);
            t[3] = __builtin_amdgcn_exp2f(L2E * t[1]);
            zE[base + (jj ^ xr)] = t;
        }
    }
    __syncthreads();

    float wv[Pdim][Fdim];
#pragma unroll
    for (int p = 0; p < Pdim; ++p)
#pragma unroll
        for (int f = 0; f < Fdim; ++f) wv[p][f] = wsm[p * Fdim + f];

    const size_t plane = (size_t)Bdim * CIN;

#pragma unroll
    for (int k = 0; k < 4; ++k) {
        const int idx = k * 512 + tid;
        int c, g = 0, q = 0;
        if (MODE == 0) { g = idx >> 9; q = idx & 511; c = q * 4 + g; }
        else           { c = idx; }

#pragma unroll
        for (int p = 0; p < Pdim; ++p) {
            const int2 jj = *(const int2*)(perm + p * Mdim + 2 * c);
            const f32x4 c0 = zE[jj.x];
            const f32x4 c1 = zE[jj.y];

#pragma unroll
            for (int r = 0; r < 2; ++r) {
                const float z0 = c0[r],     z1 = c1[r];
                const float E0 = c0[2 + r], E1 = c1[2 + r];

                const float mx = fmaxf(z0, z1);
                const float pr = z0 * z1;
                const float a1 = copysignf(__builtin_amdgcn_sqrtf(fabsf(pr) + 1e-12f), pr);
                const float a2 = z0 * E0 * E1 *
                                 __builtin_amdgcn_rcpf((1.f + E0) * (1.f + E1));
                const float a3 = __builtin_amdgcn_sqrtf(z0 * z0 + z1 * z1 + 1e-12f);
                const float a4 = fmaxf(fabsf(z0), fabsf(z1));
                const float a5 = LN2 * __builtin_amdgcn_logf(E0 + E1);

                const float v = wv[p][0] * mx + wv[p][1] * a1 + wv[p][2] * a2 +
                                wv[p][3] * a3 + wv[p][4] * a4 + wv[p][5] * a5;

                if (MODE == 0)
                    out[g * plane + (size_t)(b0 + r) * CIN + p * 512 + q] = f2bf(v);
                else
                    out[(size_t)(b0 + r) * DNEXT + p * CH + c] = f2bf(v);
            }
        }
    }
}

// ---------------------------------------------------------------------------
extern "C" void kernel_launch(void* const* d_in, const int* in_sizes, int n_in,
                              void* d_out, int out_size, void* d_ws, size_t ws_size,
                              hipStream_t stream)
{
    const float* x     = (const float*)d_in[0];
    const int*   perms = (const int*)  d_in[1];
    const float* W     = (const float*)d_in[2];
    const float* bvec  = (const float*)d_in[3];
    const float* gamma = (const float*)d_in[4];
    const float* beta  = (const float*)d_in[5];
    const float* alpha = (const float*)d_in[6];
    const float* Wo    = (const float*)d_in[7];
    const float* bo    = (const float*)d_in[8];
    float* out = (float*)d_out;

    char* ws = (char*)d_ws;
    short* y      = (short*)ws;                             // B*M bf16 (grouped cols)
    short* hg     = y + (size_t)Bdim * Mdim;                // G*B*CIN bf16 (also hflat)
    short* Wlb3   = hg + (size_t)Gdim * Bdim * CIN;         // 3*G*MG*CIN bf16 (all layers)
    short* Wob    = Wlb3 + (size_t)Lnum * Gdim * MG * CIN;  // 1024*8192 bf16
    float* psum   = (float*)(Wob + (size_t)1024 * DNEXT);
    float* psumsq = psum + (size_t)NRCHUNK * Mdim;
    float* scale  = psumsq + (size_t)NRCHUNK * Mdim;
    float* shift  = scale + Mdim;
    float* wsm    = shift + Mdim;
    int*   perm_g = (int*)(wsm + Lnum * Pdim * Fdim);       // L*P*M ints

    short* hflat = hg;           // layer-2 combinact output aliases hg (dead then)
    float* part  = (float*)Wlb3; // out-GEMM partials alias Wlb3 (dead then), 32 MB

    alpha_softmax<<<1, 64, 0, stream>>>(alpha, wsm);
    remap_perms<<<(Lnum * Pdim * Mdim) / 256, 256, 0, stream>>>(
        perms, perm_g, Lnum * Pdim * Mdim);
    convert_f32_bf16<<<(Lnum * Gdim * MG * CIN / 8) / 256, 256, 0, stream>>>(
        W, Wlb3, Lnum * Gdim * MG * CIN / 8);
    convert_wo<<<(1024 * 1024) / 256, 256, 0, stream>>>(Wo, Wob);
    x_to_grouped<<<dim3(CIN / 256, Bdim), 256, 0, stream>>>(x, hg);

    const size_t planeA = (size_t)Bdim * CIN;
    const size_t planeB = (size_t)MG * CIN;

    for (int l = 0; l < Lnum; ++l) {
        // y[b][g*1024+m] bf16, contiguous stores; BN partial stats fused.
        dim3 gg(MG / 128, Bdim / 128, Gdim);
        gemm_mfma<true, short><<<gg, 512, 0, stream>>>(
            hg, planeA, CIN, Wlb3 + (size_t)l * Gdim * MG * CIN, planeB, CIN,
            bvec + (size_t)l * Gdim * MG, (size_t)MG,
            y, (size_t)MG,
            CIN, Mdim, MG,
            psum, psumsq, MG);

        bn_finalize<<<Mdim / 256, 256, 0, stream>>>(
            psum, psumsq, gamma + (size_t)l * Mdim, beta + (size_t)l * Mdim, scale, shift);

        if (l < Lnum - 1)
            combinact_kernel<0><<<Bdim / 2, 512, 0, stream>>>(
                y, scale, shift, perm_g + (size_t)l * Pdim * Mdim, wsm + l * Pdim * Fdim, hg);
        else
            combinact_kernel<1><<<Bdim / 2, 512, 0, stream>>>(
                y, scale, shift, perm_g + (size_t)l * Pdim * Mdim, wsm + l * Pdim * Fdim, hflat);
    }

    // Output GEMM, split-K=4 (K=2048 each), partials in Wlb3 region, then reduce.
    dim3 go(1024 / 128, Bdim / 128, 4);
    gemm_mfma<false, float><<<go, 512, 0, stream>>>(
        hflat, (size_t)2048, DNEXT, Wob, (size_t)2048, DNEXT,
        nullptr, 0,
        part, (size_t)Bdim * 1024,
        2048, 1024, 1024,
        nullptr, nullptr, 0);

    dim3 gr(4, Bdim);
    reduce_out<<<gr, 256, 0, stream>>>(part, bo, out);
}

// Round 15
// 297.611 us; speedup vs baseline: 1.2473x; 1.1101x over previous
//
#include <hip/hip_runtime.h>
#include <math.h>

#define Lnum 3
#define Mdim 4096
#define Pdim 4
#define Gdim 4
#define NIN 8192
#define NOUT 1000
#define Bdim 2048
#define Fdim 6
#define CIN 2048      // input channels per group (all layers)
#define MG 1024       // M / G
#define CH 2048       // M / K
#define DNEXT 8192
#define NRCHUNK (Bdim / 128)   // 16 row-blocks of 128 = GEMM tile rows

typedef short bf16x8 __attribute__((ext_vector_type(8)));
typedef float f32x4 __attribute__((ext_vector_type(4)));

__device__ __forceinline__ short f2bf(float f) {
    union { float f; unsigned u; } v; v.f = f;
    unsigned u = v.u;
    unsigned r = (u + 0x7fffu + ((u >> 16) & 1u)) >> 16;
    return (short)r;
}
__device__ __forceinline__ float bf2f(short h) {
    union { unsigned u; float f; } x;
    x.u = ((unsigned)(unsigned short)h) << 16;
    return x.f;
}

// ---------------------------------------------------------------------------
__global__ __launch_bounds__(256) void convert_f32_bf16(
    const float* __restrict__ src, short* __restrict__ dst, int n8)
{
    int i = blockIdx.x * 256 + threadIdx.x;
    if (i >= n8) return;
    const float4* s = (const float4*)src + (size_t)i * 2;
    float4 v0 = s[0], v1 = s[1];
    bf16x8 o;
    o[0] = f2bf(v0.x); o[1] = f2bf(v0.y); o[2] = f2bf(v0.z); o[3] = f2bf(v0.w);
    o[4] = f2bf(v1.x); o[5] = f2bf(v1.y); o[6] = f2bf(v1.z); o[7] = f2bf(v1.w);
    *((bf16x8*)dst + i) = o;
}

// Wo (1000 x 8192) f32 -> padded (1024 x 8192) bf16, pad rows zero
__global__ __launch_bounds__(256) void convert_wo(
    const float* __restrict__ src, short* __restrict__ dst)
{
    int i = blockIdx.x * 256 + threadIdx.x;
    int row = i >> 10;
    bf16x8 o;
    if (row < NOUT) {
        const float4* s = (const float4*)(src + (size_t)row * DNEXT + (i & 1023) * 8);
        float4 v0 = s[0], v1 = s[1];
        o[0] = f2bf(v0.x); o[1] = f2bf(v0.y); o[2] = f2bf(v0.z); o[3] = f2bf(v0.w);
        o[4] = f2bf(v1.x); o[5] = f2bf(v1.y); o[6] = f2bf(v1.z); o[7] = f2bf(v1.w);
    } else {
        for (int j = 0; j < 8; ++j) o[j] = 0;
    }
    *((bf16x8*)dst + i) = o;
}

// x (B x 8192) f32 -> grouped bf16 planes hg[g][b][c] = x[b][4c+g]
__global__ __launch_bounds__(256) void x_to_grouped(
    const float* __restrict__ x, short* __restrict__ hg)
{
    const int c = blockIdx.x * 256 + threadIdx.x;
    const int b = blockIdx.y;
    float4 v = *(const float4*)(x + (size_t)b * NIN + 4 * c);
    const size_t plane = (size_t)Bdim * CIN;
    hg[0 * plane + (size_t)b * CIN + c] = f2bf(v.x);
    hg[1 * plane + (size_t)b * CIN + c] = f2bf(v.y);
    hg[2 * plane + (size_t)b * CIN + c] = f2bf(v.z);
    hg[3 * plane + (size_t)b * CIN + c] = f2bf(v.w);
}

// perm value remap: original j -> grouped col jg = (j&3)*1024 + (j>>2),
// then fold the combinact LDS bank swizzle: js = jg ^ ((jg>>3)&3).
__global__ __launch_bounds__(256) void remap_perms(
    const int* __restrict__ perm, int* __restrict__ perm_g, int n)
{
    int i = blockIdx.x * 256 + threadIdx.x;
    if (i >= n) return;
    int j  = perm[i];
    int jg = ((j & 3) << 10) | (j >> 2);
    perm_g[i] = jg ^ ((jg >> 3) & 3);
}

// ---------------------------------------------------------------------------
// MFMA bf16 GEMM (R12 structure — the verified local optimum): both operands
// bf16 via global_load_lds (pre-swizzled source slot), double-buffered BK=64,
// counted vmcnt(4). Tile 128x128, 8 waves (2x4), wave tile 64x32 per K-half.
// If STATS: fused per-column partial sums -> psum/psumsq[by*Mdim+g*sgz+n0+col].
// ---------------------------------------------------------------------------
template<int BN_T, int NWARP, bool STATS, typename CT>
__global__ __launch_bounds__(NWARP * 64) void gemm_mfma(
    const short* __restrict__ A0, size_t aZ, int lda,
    const short* __restrict__ B0, size_t bZ, int ldb,
    const float* __restrict__ bias0, size_t biasZ,
    CT* __restrict__ C0, size_t cZ,
    int K, int ldc, int nbound,
    float* __restrict__ psum, float* __restrict__ psumsq, int sgz)
{
    constexpr int NT   = NWARP * 64;
    constexpr int WCN  = NWARP / 2;       // waves along N
    constexpr int WCOL = BN_T / WCN;      // cols per wave
    constexpr int FN   = WCOL / 16;       // 16-col frags per wave

    // XCD-aware swizzle (nwg % 8 == 0 in all our launches)
    const int nx = gridDim.x, ny = gridDim.y;
    const int nwg = nx * ny * gridDim.z;
    const int lin = blockIdx.x + nx * (blockIdx.y + ny * blockIdx.z);
    int swz = (lin & 7) * (nwg >> 3) + (lin >> 3);
    const int bx = swz % nx; swz /= nx;
    const int by = swz % ny;
    const int g  = swz / ny;

    const short* A  = A0 + aZ * g;
    const short* Bm = B0 + bZ * g;
    CT* C = C0 + cZ * g;

    const int n0 = bx * BN_T;
    const int b0 = by * 128;

    __shared__ short As[2][128 * 64];
    __shared__ short Bs[2][BN_T * 64];

    const int tid  = threadIdx.x;
    const int w    = tid >> 6;
    const int lane = tid & 63;
    const int wr = w / WCN, wc = w % WCN;

    f32x4 acc[4][FN];
#pragma unroll
    for (int m = 0; m < 4; ++m)
#pragma unroll
        for (int n = 0; n < FN; ++n) acc[m][n] = (f32x4)0.f;

    auto stage = [&](int buf, int k0) {
#pragma unroll
        for (int idx = tid; idx < 128 * 8; idx += NT) {
            const int r = idx >> 3, slot = idx & 7;
            const int gs = slot ^ (r & 7);
            const short* ga = A + (size_t)(b0 + r) * lda + k0 + gs * 8;
            __builtin_amdgcn_global_load_lds(
                (const __attribute__((address_space(1))) void*)ga,
                (__attribute__((address_space(3))) void*)(&As[buf][idx * 8]), 16, 0, 0);
        }
#pragma unroll
        for (int idx = tid; idx < BN_T * 8; idx += NT) {
            const int r = idx >> 3, slot = idx & 7;
            const int gs = slot ^ (r & 7);
            const short* gb = Bm + (size_t)(n0 + r) * ldb + k0 + gs * 8;
            __builtin_amdgcn_global_load_lds(
                (const __attribute__((address_space(1))) void*)gb,
                (__attribute__((address_space(3))) void*)(&Bs[buf][idx * 8]), 16, 0, 0);
        }
    };

    const int fr15 = lane & 15;
    const int fq   = lane >> 4;

    auto compute = [&](int buf) {
#pragma unroll
        for (int kk = 0; kk < 2; ++kk) {
            bf16x8 af[4], bff[FN];
            const int kob = kk * 64 + fq * 16;
#pragma unroll
            for (int m = 0; m < 4; ++m) {
                const int r  = wr * 64 + m * 16 + fr15;
                const int sw = kob ^ ((r & 7) << 4);
                af[m] = *(const bf16x8*)(&As[buf][r * 64 + (sw >> 1)]);
            }
#pragma unroll
            for (int n = 0; n < FN; ++n) {
                const int r  = wc * WCOL + n * 16 + fr15;
                const int sw = kob ^ ((r & 7) << 4);
                bff[n] = *(const bf16x8*)(&Bs[buf][r * 64 + (sw >> 1)]);
            }
#pragma unroll
            for (int m = 0; m < 4; ++m)
#pragma unroll
                for (int n = 0; n < FN; ++n)
                    acc[m][n] = __builtin_amdgcn_mfma_f32_16x16x32_bf16(af[m], bff[n], acc[m][n], 0, 0, 0);
        }
    };

    stage(0, 0);

    const int nt = K >> 6;   // even (K multiple of 128)
    int p = 0;
    for (int t = 0; t < nt - 1; ++t) {
        stage(p ^ 1, (t + 1) << 6);
        asm volatile("s_waitcnt vmcnt(4)" ::: "memory");
        __builtin_amdgcn_s_barrier();
        asm volatile("" ::: "memory");
        compute(p);
        asm volatile("" ::: "memory");
        __builtin_amdgcn_s_barrier();
        p ^= 1;
    }
    asm volatile("s_waitcnt vmcnt(0)" ::: "memory");
    __builtin_amdgcn_s_barrier();
    asm volatile("" ::: "memory");
    compute(p);

    float s[FN], ss[FN];
#pragma unroll
    for (int n = 0; n < FN; ++n) { s[n] = 0.f; ss[n] = 0.f; }

#pragma unroll
    for (int m = 0; m < 4; ++m) {
#pragma unroll
        for (int n = 0; n < FN; ++n) {
#pragma unroll
            for (int j = 0; j < 4; ++j) {
                const int row = b0 + wr * 64 + m * 16 + fq * 4 + j;
                const int col = n0 + wc * WCOL + n * 16 + fr15;
                if (col < nbound) {
                    float v = acc[m][n][j];
                    if (bias0) v += bias0[biasZ * g + col];
                    C[(size_t)row * ldc + col] = (CT)(sizeof(CT) == 2 ? (CT)f2bf(v) : (CT)v);
                    if (STATS) { s[n] += v; ss[n] += v * v; }
                }
            }
        }
    }

    if (STATS) {
        __syncthreads();   // all waves done with LDS compute buffers
        float* sum_lds = (float*)&As[0][0];
        float* ssq_lds = sum_lds + BN_T * 8;
        const int slot = wr * 4 + fq;
#pragma unroll
        for (int n = 0; n < FN; ++n) {
            const int cl = wc * WCOL + n * 16 + fr15;
            sum_lds[cl * 8 + slot] = s[n];
            ssq_lds[cl * 8 + slot] = ss[n];
        }
        __syncthreads();
        for (int cl = tid; cl < BN_T; cl += NT) {
            float a = 0.f, b = 0.f;
#pragma unroll
            for (int q = 0; q < 8; ++q) {
                a += sum_lds[cl * 8 + q];
                b += ssq_lds[cl * 8 + q];
            }
            const size_t o = (size_t)by * Mdim + g * sgz + n0 + cl;
            psum[o]   = a;
            psumsq[o] = b;
        }
    }
}

// out[b,n] = sum_z p[z][b,n] + bo[n], 4 split-K partials
__global__ __launch_bounds__(256) void reduce_out(
    const float* __restrict__ part, const float* __restrict__ bo,
    float* __restrict__ out)
{
    const int n = blockIdx.x * 256 + threadIdx.x;
    const int b = blockIdx.y;
    if (n >= NOUT) return;
    const size_t S = (size_t)Bdim * 1024;
    const size_t i = (size_t)b * 1024 + n;
    out[(size_t)b * NOUT + n] =
        part[i] + part[S + i] + part[2 * S + i] + part[3 * S + i] + bo[n];
}

// ---------------------------------------------------------------------------
// Columns are in GROUPED order jg = g*1024+m  (orig j = (jg&1023)*4 + jg>>10)
__global__ __launch_bounds__(256) void bn_finalize(
    const float* __restrict__ psum, const float* __restrict__ psumsq,
    const float* __restrict__ gamma, const float* __restrict__ beta,
    float* __restrict__ scale, float* __restrict__ shift)
{
    const int jg = blockIdx.x * 256 + threadIdx.x;
    if (jg >= Mdim) return;
    const int j = ((jg & 1023) << 2) | (jg >> 10);
    float s = 0.f, ss = 0.f;
    for (int r = 0; r < NRCHUNK; ++r) {
        s  += psum[r * Mdim + jg];
        ss += psumsq[r * Mdim + jg];
    }
    const float mu  = s * (1.f / Bdim);
    const float var = ss * (1.f / Bdim) - mu * mu;
    const float sc  = gamma[j] * rsqrtf(var + 1e-5f);
    scale[jg] = sc;
    shift[jg] = beta[j] - mu * sc;
}

__global__ void alpha_softmax(const float* __restrict__ alpha, float* __restrict__ wsm)
{
    const int idx = threadIdx.x;
    if (idx >= Lnum * Pdim) return;
    const float* a = alpha + idx * Fdim;
    float mx = a[0];
#pragma unroll
    for (int f = 1; f < Fdim; ++f) mx = fmaxf(mx, a[f]);
    float e[Fdim]; float s = 0.f;
#pragma unroll
    for (int f = 0; f < Fdim; ++f) { e[f] = __expf(a[f] - mx); s += e[f]; }
    const float inv = 1.f / s;
#pragma unroll
    for (int f = 0; f < Fdim; ++f) wsm[idx * Fdim + f] = e[f] * inv;
}

// ---------------------------------------------------------------------------
// Fused normalize + gather + combinact, 2 rows/block, 512 threads (8 waves).
// E=e^z precomputed at staging:
//   sig(z0)*sig(z1) = E0*E1/((1+E0)(1+E1));  lse = LN2*log2(E0+E1).
// LDS: per col f32x4 {z_r0, z_r1, E_r0, E_r1}, bank-swizzled (perm pre-folded).
// MODE 0: grouped planes hg[g][b][p*512+q], c=q*4+g ; MODE 1: flat h[b][p*CH+c]
// ---------------------------------------------------------------------------
template<int MODE>
__global__ __launch_bounds__(512) void combinact_kernel(
    const short* __restrict__ Y, const float* __restrict__ scale,
    const float* __restrict__ shift, const int* __restrict__ perm,
    const float* __restrict__ wsm, short* __restrict__ out)
{
    __shared__ f32x4 zE[Mdim];           // 64 KB
    const int b0  = blockIdx.x * 2;
    const int tid = threadIdx.x;
    const float L2E = 1.44269504f;
    const float LN2 = 0.69314718f;

    {
        const int i8   = tid;            // 512 chunks of 8 cols, 1 per thread
        const int base = i8 * 8;
        const bf16x8 v0 = *((const bf16x8*)(Y + (size_t)(b0 + 0) * Mdim) + i8);
        const bf16x8 v1 = *((const bf16x8*)(Y + (size_t)(b0 + 1) * Mdim) + i8);
        const int xr = i8 & 3;           // bank swizzle: js = j ^ ((j>>3)&3)
#pragma unroll
        for (int jj = 0; jj < 8; ++jj) {
            const float sc = scale[base + jj];
            const float sh = shift[base + jj];
            f32x4 t;
            t[0] = bf2f(v0[jj]) * sc + sh;
            t[1] = bf2f(v1[jj]) * sc + sh;
            t[2] = __builtin_amdgcn_exp2f(L2E * t[0]);
            t[3] = __builtin_amdgcn_exp2f(L2E * t[1]);
            zE[base + (jj ^ xr)] = t;
        }
    }
    __syncthreads();

    float wv[Pdim][Fdim];
#pragma unroll
    for (int p = 0; p < Pdim; ++p)
#pragma unroll
        for (int f = 0; f < Fdim; ++f) wv[p][f] = wsm[p * Fdim + f];

    const size_t plane = (size_t)Bdim * CIN;

#pragma unroll
    for (int k = 0; k < 4; ++k) {
        const int idx = k * 512 + tid;
        int c, g = 0, q = 0;
        if (MODE == 0) { g = idx >> 9; q = idx & 511; c = q * 4 + g; }
        else           { c = idx; }

#pragma unroll
        for (int p = 0; p < Pdim; ++p) {
            const int2 jj = *(const int2*)(perm + p * Mdim + 2 * c);
            const f32x4 c0 = zE[jj.x];
            const f32x4 c1 = zE[jj.y];

#pragma unroll
            for (int r = 0; r < 2; ++r) {
                const float z0 = c0[r],     z1 = c1[r];
                const float E0 = c0[2 + r], E1 = c1[2 + r];

                const float mx = fmaxf(z0, z1);
                const float pr = z0 * z1;
                const float a1 = copysignf(__builtin_amdgcn_sqrtf(fabsf(pr) + 1e-12f), pr);
                const float a2 = z0 * E0 * E1 *
                                 __builtin_amdgcn_rcpf((1.f + E0) * (1.f + E1));
                const float a3 = __builtin_amdgcn_sqrtf(z0 * z0 + z1 * z1 + 1e-12f);
                const float a4 = fmaxf(fabsf(z0), fabsf(z1));
                const float a5 = LN2 * __builtin_amdgcn_logf(E0 + E1);

                const float v = wv[p][0] * mx + wv[p][1] * a1 + wv[p][2] * a2 +
                                wv[p][3] * a3 + wv[p][4] * a4 + wv[p][5] * a5;

                if (MODE == 0)
                    out[g * plane + (size_t)(b0 + r) * CIN + p * 512 + q] = f2bf(v);
                else
                    out[(size_t)(b0 + r) * DNEXT + p * CH + c] = f2bf(v);
            }
        }
    }
}

// ---------------------------------------------------------------------------
extern "C" void kernel_launch(void* const* d_in, const int* in_sizes, int n_in,
                              void* d_out, int out_size, void* d_ws, size_t ws_size,
                              hipStream_t stream)
{
    const float* x     = (const float*)d_in[0];
    const int*   perms = (const int*)  d_in[1];
    const float* W     = (const float*)d_in[2];
    const float* bvec  = (const float*)d_in[3];
    const float* gamma = (const float*)d_in[4];
    const float* beta  = (const float*)d_in[5];
    const float* alpha = (const float*)d_in[6];
    const float* Wo    = (const float*)d_in[7];
    const float* bo    = (const float*)d_in[8];
    float* out = (float*)d_out;

    char* ws = (char*)d_ws;
    short* y      = (short*)ws;                             // B*M bf16 (grouped cols)
    short* hg     = y + (size_t)Bdim * Mdim;                // G*B*CIN bf16 (also hflat)
    short* Wlb3   = hg + (size_t)Gdim * Bdim * CIN;         // 3*G*MG*CIN bf16 (all layers)
    short* Wob    = Wlb3 + (size_t)Lnum * Gdim * MG * CIN;  // 1024*8192 bf16
    float* psum   = (float*)(Wob + (size_t)1024 * DNEXT);
    float* psumsq = psum + (size_t)NRCHUNK * Mdim;
    float* scale  = psumsq + (size_t)NRCHUNK * Mdim;
    float* shift  = scale + Mdim;
    float* wsm    = shift + Mdim;
    int*   perm_g = (int*)(wsm + Lnum * Pdim * Fdim);       // L*P*M ints

    short* hflat = hg;           // layer-2 combinact output aliases hg (dead then)
    float* part  = (float*)Wlb3; // out-GEMM partials alias Wlb3 (dead then), 32 MB

    alpha_softmax<<<1, 64, 0, stream>>>(alpha, wsm);
    remap_perms<<<(Lnum * Pdim * Mdim) / 256, 256, 0, stream>>>(
        perms, perm_g, Lnum * Pdim * Mdim);
    convert_f32_bf16<<<(Lnum * Gdim * MG * CIN / 8) / 256, 256, 0, stream>>>(
        W, Wlb3, Lnum * Gdim * MG * CIN / 8);
    convert_wo<<<(1024 * 1024) / 256, 256, 0, stream>>>(Wo, Wob);
    x_to_grouped<<<dim3(CIN / 256, Bdim), 256, 0, stream>>>(x, hg);

    const size_t planeA = (size_t)Bdim * CIN;
    const size_t planeB = (size_t)MG * CIN;

    for (int l = 0; l < Lnum; ++l) {
        // y[b][g*1024+m] bf16, contiguous stores; BN partial stats fused.
        dim3 gg(MG / 128, Bdim / 128, Gdim);
        gemm_mfma<128, 8, true, short><<<gg, 512, 0, stream>>>(
            hg, planeA, CIN, Wlb3 + (size_t)l * Gdim * MG * CIN, planeB, CIN,
            bvec + (size_t)l * Gdim * MG, (size_t)MG,
            y, (size_t)MG,
            CIN, Mdim, MG,
            psum, psumsq, MG);

        bn_finalize<<<Mdim / 256, 256, 0, stream>>>(
            psum, psumsq, gamma + (size_t)l * Mdim, beta + (size_t)l * Mdim, scale, shift);

        if (l < Lnum - 1)
            combinact_kernel<0><<<Bdim / 2, 512, 0, stream>>>(
                y, scale, shift, perm_g + (size_t)l * Pdim * Mdim, wsm + l * Pdim * Fdim, hg);
        else
            combinact_kernel<1><<<Bdim / 2, 512, 0, stream>>>(
                y, scale, shift, perm_g + (size_t)l * Pdim * Mdim, wsm + l * Pdim * Fdim, hflat);
    }

    // Output GEMM, split-K=4 (K=2048 each), partials in Wlb3 region, then reduce.
    dim3 go(1024 / 128, Bdim / 128, 4);
    gemm_mfma<128, 8, false, float><<<go, 512, 0, stream>>>(
        hflat, (size_t)2048, DNEXT, Wob, (size_t)2048, DNEXT,
        nullptr, 0,
        part, (size_t)Bdim * 1024,
        2048, 1024, 1024,
        nullptr, nullptr, 0);

    dim3 gr(4, Bdim);
    reduce_out<<<gr, 256, 0, stream>>>(part, bo, out);
}